// Round 15
// baseline (420.615 us; speedup 1.0000x reference)
//
#include <hip/hip_runtime.h>
#include <hip/hip_fp8.h>
#include <math.h>

// ---------------------------------------------------------------------------
// GATClassifier on MI355X.
//   1. CSR build over dst: striped histogram -> 3-phase scan -> dst-striped
//      scatter (stripe = bid&7 pins each dst range's atomics+stores to one
//      XCD; heuristic only). col_s 4B only.
//   2. Per layer: MFMA GEMM h = bf16(A) @ bf16(B). R19 single-barrier
//      full-A-stage GEMM (64x256 A-strip in 32KB LDS, fragment-ordered,
//      barrier-free k-loop; R27 1-step B prefetch). R21 att dots fused into
//      epilogue. R25 dead Hh stores dropped. R26 Cf8 via LDS h-spill:
//      hw-packed (v_cvt_pk_fp8_f32) coalesced dwordx4 stores.
//      agg8f = R20 structure + R24 pk MAC + R28 FULL 2-deep pipeline:
//      iter i issues col_s/Hf8/aS loads for i+8 at loop top, then runs
//      exp+MAC on data loaded in iter i-1 — the gather gets a whole MAC
//      phase to land (R27 only prefetched indices: 49.2->47.4; traffic
//      floor is ~38us so the residual is exposed gather latency).
//      s_setprio(1) around the MAC cluster (T5: helps barrier-free
//      phase-diverse waves; the GEMM lockstep null doesn't apply here).
//   3. Fused mean-pool + 32->1 linear (batch sorted -> binary search)
// History: R12 gemm 57x2. R14 drop Bl (512). R15 striped scatter (506).
// R18 drop lo-terms (488). R19 single-barrier GEMM (483). R20 agg8f fused
// alpha (463). R21 col_s + att-in-GEMM (448). R22 REGRESSED (455).
// R23 neutral (449). R24 pk_fma + layer3-att-fusion (442). R25 drop dead
// Hh stores + merged prep (428). R26 coalesced Cf8 epilogue (412).
// R27 index-prefetch pipelining (408; agg8f 47.4x2, floor ~38+latency).
// R28 full 2-deep gather pipeline + setprio (resubmit: infra failure).
// NOTE: edge_index / batch are int32.
// ---------------------------------------------------------------------------

typedef __attribute__((ext_vector_type(8))) __bf16 bf16x8;
typedef __attribute__((ext_vector_type(4))) __bf16 bf16x4;
typedef __attribute__((ext_vector_type(4))) float f32x4;
typedef __attribute__((ext_vector_type(2))) float f32x2;

#define SCAN_CH 4  // elements per thread in the device-wide scan

__device__ inline unsigned char f32_to_fp8(float f) {
  __hip_fp8_e4m3 v(f);
  return (unsigned char)v.__x;
}
__device__ inline float fp8_to_f32(unsigned char u) {
  __hip_fp8_e4m3 v;
  v.__x = (__hip_fp8_storage_t)u;
  return (float)v;
}

// Pack 4 f32 -> 4 fp8-e4m3 bytes in one dword (hw v_cvt_pk_fp8_f32 pair).
__device__ inline unsigned int pack4_fp8(float f0, float f1, float f2,
                                         float f3) {
#if defined(__has_builtin) && __has_builtin(__builtin_amdgcn_cvt_pk_fp8_f32)
  int w = 0;
  w = __builtin_amdgcn_cvt_pk_fp8_f32(f0, f1, w, false);  // bytes 0,1
  w = __builtin_amdgcn_cvt_pk_fp8_f32(f2, f3, w, true);   // bytes 2,3
  return (unsigned int)w;
#else
  return (unsigned int)f32_to_fp8(f0) | ((unsigned int)f32_to_fp8(f1) << 8) |
         ((unsigned int)f32_to_fp8(f2) << 16) |
         ((unsigned int)f32_to_fp8(f3) << 24);
#endif
}

// Decode 4 packed fp8 bytes -> 2 f32x2, packed-FMA into pair accumulators.
// f32x2 math maps to v_pk_fma_f32 (1 inst = 2 FMAs).
__device__ inline void fma_fp8x4_pk(f32x2& aLo, f32x2& aHi, f32x2 w2,
                                    unsigned int packed) {
#if defined(__has_builtin) && __has_builtin(__builtin_amdgcn_cvt_pk_f32_fp8)
  f32x2 lo = __builtin_amdgcn_cvt_pk_f32_fp8((int)packed, false);  // b0,b1
  f32x2 hi = __builtin_amdgcn_cvt_pk_f32_fp8((int)packed, true);   // b2,b3
  aLo = __builtin_elementwise_fma(lo, w2, aLo);
  aHi = __builtin_elementwise_fma(hi, w2, aHi);
#else
  aLo[0] += w2[0] * fp8_to_f32((unsigned char)(packed & 0xff));
  aLo[1] += w2[1] * fp8_to_f32((unsigned char)((packed >> 8) & 0xff));
  aHi[0] += w2[0] * fp8_to_f32((unsigned char)((packed >> 16) & 0xff));
  aHi[1] += w2[1] * fp8_to_f32((unsigned char)(packed >> 24));
#endif
}

// ---------------- merged prep: x cast + 3 W transposes + init_deg --------
__global__ __launch_bounds__(256) void k_prep(
    const float* __restrict__ x, __bf16* __restrict__ Ah,
    const float* __restrict__ W1, __bf16* __restrict__ WT1h,
    const float* __restrict__ W2, __bf16* __restrict__ WT2h,
    const float* __restrict__ W3, __bf16* __restrict__ WT3h,
    int* __restrict__ deg, int N) {
  int b = blockIdx.x;
  const int nCast = (N * 64 + 255) / 256;
  if (b < nCast) {  // cast x -> bf16 (float4 per thread)
    int i = b * 256 + threadIdx.x;
    if (i < N * 64) {
      float4 v = ((const float4*)x)[i];
      bf16x4 h;
      h[0] = (__bf16)v.x;
      h[1] = (__bf16)v.y;
      h[2] = (__bf16)v.z;
      h[3] = (__bf16)v.w;
      ((bf16x4*)Ah)[i] = h;
    }
    return;
  }
  b -= nCast;
  if (b < 256) {  // WT1: [256][256], i = n*256 + k
    int i = b * 256 + threadIdx.x;
    int n = i >> 8, k = i & 255;
    WT1h[i] = (__bf16)W1[k * 256 + n];
    return;
  }
  b -= 256;
  if (b < 256) {  // WT2
    int i = b * 256 + threadIdx.x;
    int n = i >> 8, k = i & 255;
    WT2h[i] = (__bf16)W2[k * 256 + n];
    return;
  }
  b -= 256;
  if (b < 32) {  // WT3: [32][256], Nc = 32
    int i = b * 256 + threadIdx.x;
    int n = i >> 8, k = i & 255;
    WT3h[i] = (__bf16)W3[k * 32 + n];
    return;
  }
  b -= 32;
  {  // init_deg
    int n = b * 256 + threadIdx.x;
    if (n < N) deg[n] = 1;  // self-loop
  }
}

// ---------------- CSR build ----------------
// dst-striped degree histogram (R23).
__global__ __launch_bounds__(256) void k_count_deg_s(const int* __restrict__ ei,
                                                     int E, int N, int* deg,
                                                     int chunkSz) {
  int stripe = blockIdx.x & 7;
  int chunk = blockIdx.x >> 3;
  int lo = (int)(((long long)N * stripe) >> 3);
  int hi = (int)(((long long)N * (stripe + 1)) >> 3);
  int base = chunk * chunkSz;
  int end = base + chunkSz;
  if (end > E) end = E;
  for (int i = base + threadIdx.x; i < end; i += 256) {
    int d = ei[E + i];
    if (d >= lo && d < hi) atomicAdd(&deg[d], 1);
  }
}

// --- 3-phase exclusive scan (R8: old single-block scan was 111us on 1 CU) ---
__global__ __launch_bounds__(256) void k_scan_partial(const int* __restrict__ deg,
                                                      int* __restrict__ blockSums,
                                                      int N) {
  __shared__ int sh[256];
  int t = threadIdx.x, b = blockIdx.x;
  int base = (b * 256 + t) * SCAN_CH;
  int s = 0;
#pragma unroll
  for (int j = 0; j < SCAN_CH; j++) {
    int idx = base + j;
    if (idx < N) s += deg[idx];
  }
  sh[t] = s;
  __syncthreads();
  for (int off = 128; off > 0; off >>= 1) {
    if (t < off) sh[t] += sh[t + off];
    __syncthreads();
  }
  if (t == 0) blockSums[b] = sh[0];
}

__global__ __launch_bounds__(256) void k_scan_blocksums(
    const int* __restrict__ blockSums, int* __restrict__ blockOffs,
    int* __restrict__ rowptr, int nb, int N) {
  __shared__ int sh[256];
  int t = threadIdx.x;
  int v = (t < nb) ? blockSums[t] : 0;
  sh[t] = v;
  __syncthreads();
  for (int off = 1; off < 256; off <<= 1) {
    int u = (t >= off) ? sh[t - off] : 0;
    __syncthreads();
    sh[t] += u;
    __syncthreads();
  }
  if (t < nb) blockOffs[t] = sh[t] - v;  // exclusive
  if (t == nb - 1) rowptr[N] = sh[t];    // total
}

__global__ __launch_bounds__(256) void k_scan_final(const int* __restrict__ deg,
                                                    const int* __restrict__ blockOffs,
                                                    int* __restrict__ rowptr,
                                                    int* __restrict__ cursor, int N) {
  __shared__ int sh[256];
  int t = threadIdx.x, b = blockIdx.x;
  int base = (b * 256 + t) * SCAN_CH;
  int vals[SCAN_CH];
  int s = 0;
#pragma unroll
  for (int j = 0; j < SCAN_CH; j++) {
    int idx = base + j;
    vals[j] = (idx < N) ? deg[idx] : 0;
    s += vals[j];
  }
  sh[t] = s;
  __syncthreads();
  for (int off = 1; off < 256; off <<= 1) {
    int u = (t >= off) ? sh[t - off] : 0;
    __syncthreads();
    sh[t] += u;
    __syncthreads();
  }
  int run = blockOffs[b] + sh[t] - s;  // exclusive prefix for this thread
#pragma unroll
  for (int j = 0; j < SCAN_CH; j++) {
    int idx = base + j;
    if (idx < N) {
      rowptr[idx] = run;
      cursor[idx] = run;
      run += vals[j];
    }
  }
}

// dst-striped scatter (R15/R21). Single 4B src store per edge.
__global__ __launch_bounds__(256) void k_scatter2(const int* __restrict__ ei,
                                                  int E, int N, int* cursor,
                                                  int* __restrict__ col_s,
                                                  int chunkSz) {
  int stripe = blockIdx.x & 7;
  int chunk = blockIdx.x >> 3;
  int lo = (int)(((long long)N * stripe) >> 3);
  int hi = (int)(((long long)N * (stripe + 1)) >> 3);
  int base = chunk * chunkSz;
  int end = base + chunkSz;
  int total = E + N;
  if (end > total) end = total;
  for (int i = base + threadIdx.x; i < end; i += 256) {
    int d = (i < E) ? ei[E + i] : (i - E);
    if (d < lo || d >= hi) continue;
    int s = (i < E) ? ei[i] : d;
    int pos = atomicAdd(&cursor[d], 1);
    col_s[pos] = s;
  }
}

// ------- LDS-shared MFMA GEMM + fused att dots (layers 1/2) --------------
// C = Ah @ Bh, plain bf16. Block = 64 rows x 256 cols (782 blocks, 4 waves).
// Stage the WHOLE 64x256 A-strip (32KB, fragment-ordered) up front, ONE
// barrier, barrier-free k-loop (R27: 1-step B prefetch; 4 B-loads + 4 LDS
// reads + 16 MFMAs/step). Epilogue (R26): barrier, spill h bf16 into sA,
// barrier, att dots + Cf8 hw-pack coalesced stores from the LDS copy.
// mfma_f32_16x16x32_bf16 (m89-verified): A: m=lane&15,k=quad*8+j;
// B: n=lane&15,k=quad*8+j (from WT); C/D: row=quad*4+reg, col=lane&15.
__global__ __launch_bounds__(256) void k_gemm_att(
    const __bf16* __restrict__ Ah, const __bf16* __restrict__ BTh,
    const float* __restrict__ attS, const float* __restrict__ attD,
    unsigned char* __restrict__ Cf8,
    float* __restrict__ aS, float* __restrict__ aD, int M, int K) {
  __shared__ __bf16 sA[64 * 256];  // 32 KB; reused for h spill after k-loop
  __shared__ float sAttS[256], sAttD[256];
  int tid = threadIdx.x;
  int lane = tid & 63, wave = tid >> 6;
  int quad = lane >> 4, l16 = lane & 15;
  int m0 = blockIdx.x * 64;
  int col0 = wave * 64;
  sAttS[tid] = attS[tid];  // 8 heads x 32 ch
  sAttD[tid] = attD[tid];
  // ---- stage all of A (8 rounds, coalesced, fragment-ordered) ----
  int srow = tid >> 2;                  // 0..63
  int mtw = srow >> 4, l16w = srow & 15;
  int arow = min(m0 + srow, M - 1);     // clamp: rows >= M never stored
  const __bf16* ag = Ah + (size_t)arow * K;
#pragma unroll
  for (int r = 0; r < 8; r++) {
    int c = (tid & 3) + r * 4;          // 8-elem chunk 0..31
    int s = c >> 2, q = c & 3;
    int slot = (((s * 4 + mtw) * 4 + q) * 16 + l16w) * 8;
    *(bf16x8*)(sA + slot) = *(const bf16x8*)(ag + c * 8);
  }
  __syncthreads();
  const __bf16* brh = BTh + (size_t)(col0 + l16) * K + quad * 8;
  f32x4 acc[4][4];  // [mt][nt]
#pragma unroll
  for (int mt = 0; mt < 4; mt++)
#pragma unroll
    for (int t = 0; t < 4; t++) acc[mt][t] = (f32x4){0.f, 0.f, 0.f, 0.f};
  bf16x8 b_h[4], b_n[4];
#pragma unroll
  for (int t = 0; t < 4; t++)
    b_h[t] = *(const bf16x8*)(brh + (size_t)t * 16 * K);
  for (int s = 0; s < 8; s++) {  // k0 = s*32; no barriers inside
    if (s < 7) {  // prefetch B(s+1); lands under this step's MFMAs
#pragma unroll
      for (int t = 0; t < 4; t++)
        b_n[t] = *(const bf16x8*)(brh + (size_t)t * 16 * K + (s + 1) * 32);
    }
    bf16x8 a_h[4];
#pragma unroll
    for (int mt = 0; mt < 4; mt++)
      a_h[mt] = *(const bf16x8*)(sA + (((s * 4 + mt) * 4 + quad) * 16 + l16) * 8);
#pragma unroll
    for (int t = 0; t < 4; t++) {
#pragma unroll
      for (int mt = 0; mt < 4; mt++) {
        acc[mt][t] = __builtin_amdgcn_mfma_f32_16x16x32_bf16(a_h[mt], b_h[t], acc[mt][t], 0, 0, 0);
      }
    }
#pragma unroll
    for (int t = 0; t < 4; t++) b_h[t] = b_n[t];
  }
  __syncthreads();  // all sA (A-tile) reads done; safe to overwrite with h
#pragma unroll
  for (int mt = 0; mt < 4; mt++) {
#pragma unroll
    for (int t = 0; t < 4; t++) {
#pragma unroll
      for (int r = 0; r < 4; r++) {
        int row = mt * 16 + quad * 4 + r;
        sA[row * 256 + col0 + t * 16 + l16] = (__bf16)acc[mt][t][r];
      }
    }
  }
  __syncthreads();
  // ---- att dots: 512 tasks = (row 0..63, head 0..7), 2 per thread ----
#pragma unroll
  for (int u = 0; u < 2; u++) {
    int task = tid + u * 256;
    int row = task >> 3, h = task & 7;
    const __bf16* hr = sA + row * 256 + h * 32;
    float ss = 0.f, dd = 0.f;
#pragma unroll
    for (int k = 0; k < 4; k++) {
      bf16x8 a = *(const bf16x8*)(hr + k * 8);
#pragma unroll
      for (int j = 0; j < 8; j++) {
        float v = (float)a[j];
        ss += v * sAttS[h * 32 + k * 8 + j];
        dd += v * sAttD[h * 32 + k * 8 + j];
      }
    }
    int m = m0 + row;
    if (m < M) {
      aS[(size_t)m * 8 + h] = ss;
      aD[(size_t)m * 8 + h] = dd;
    }
  }
  // ---- Cf8 from LDS: 1024 16B segments, 4 per thread, coalesced ----
#pragma unroll
  for (int u = 0; u < 4; u++) {
    int seg = tid + u * 256;       // 0..1023
    int row = seg >> 4;            // 0..63
    int sc = (seg & 15) * 16;      // col start (16 fp8 = 16B)
    int m = m0 + row;
    if (m < M) {
      const __bf16* hp = sA + row * 256 + sc;
      bf16x8 h0 = *(const bf16x8*)hp;
      bf16x8 h1 = *(const bf16x8*)(hp + 8);
      uint4 w;
      w.x = pack4_fp8((float)h0[0], (float)h0[1], (float)h0[2], (float)h0[3]);
      w.y = pack4_fp8((float)h0[4], (float)h0[5], (float)h0[6], (float)h0[7]);
      w.z = pack4_fp8((float)h1[0], (float)h1[1], (float)h1[2], (float)h1[3]);
      w.w = pack4_fp8((float)h1[4], (float)h1[5], (float)h1[6], (float)h1[7]);
      *(uint4*)(Cf8 + (size_t)m * 256 + sc) = w;
    }
  }
}

// ------- MFMA GEMM + fused att (layer 3, H=1, R24) -----------------------
// 64 rows/block (4 waves x 16 rows), all 32 cols in-register (NT=2).
// After C store: aS/aD dots = 2 fma + 16-lane shfl reduce per row.
__global__ __launch_bounds__(256) void k_gemm3_att(
    const __bf16* __restrict__ Ah, const __bf16* __restrict__ BTh,
    const float* __restrict__ attS, const float* __restrict__ attD,
    __bf16* __restrict__ Ch, float* __restrict__ aS, float* __restrict__ aD,
    int M, int K) {
  int lane = threadIdx.x & 63;
  int wave = threadIdx.x >> 6;
  int quad = lane >> 4;
  int l16 = lane & 15;
  int m0 = blockIdx.x * 64 + wave * 16;
  int am = min(m0 + l16, M - 1);
  const __bf16* arh = Ah + (size_t)am * K + quad * 8;
  const __bf16* brh = BTh + (size_t)l16 * K + quad * 8;
  f32x4 acc0 = (f32x4){0.f, 0.f, 0.f, 0.f};
  f32x4 acc1 = (f32x4){0.f, 0.f, 0.f, 0.f};
  for (int k0 = 0; k0 < K; k0 += 32) {
    bf16x8 a = *(const bf16x8*)(arh + k0);
    bf16x8 b0 = *(const bf16x8*)(brh + k0);
    bf16x8 b1 = *(const bf16x8*)(brh + (size_t)16 * K + k0);
    acc0 = __builtin_amdgcn_mfma_f32_16x16x32_bf16(a, b0, acc0, 0, 0, 0);
    acc1 = __builtin_amdgcn_mfma_f32_16x16x32_bf16(a, b1, acc1, 0, 0, 0);
  }
#pragma unroll
  for (int r = 0; r < 4; r++) {
    int m = m0 + quad * 4 + r;
    if (m < M) {
      Ch[(size_t)m * 32 + l16] = (__bf16)acc0[r];
      Ch[(size_t)m * 32 + 16 + l16] = (__bf16)acc1[r];
    }
  }
  float s0 = attS[l16], s1 = attS[16 + l16];
  float d0 = attD[l16], d1 = attD[16 + l16];
#pragma unroll
  for (int r = 0; r < 4; r++) {
    float ss = acc0[r] * s0 + acc1[r] * s1;
    float dd = acc0[r] * d0 + acc1[r] * d1;
#pragma unroll
    for (int off = 1; off < 16; off <<= 1) {
      ss += __shfl_xor(ss, off, 64);
      dd += __shfl_xor(dd, off, 64);
    }
    int m = m0 + quad * 4 + r;
    if (l16 == 0 && m < M) {
      aS[m] = ss;
      aD[m] = dd;
    }
  }
}

// ------- GAT aggregation, H=8 (R20 + R24 pk MAC + R28 2-deep pipe) -------
// wave per node. lane = (edge-group g = lane>>4, channel-block c = lane&15:
// 16 fp8 channels = one dwordx4). One gather instruction serves 4 edges.
// w = exp(leaky(aS[s*8+head] + aD[n*8+head])) inline. R28: full software
// pipeline — iter i issues col_s/Hf8/aS loads for i+8, computes on data
// from i-8; gathers get a whole MAC phase to land. setprio(1) around the
// MAC cluster (barrier-free phase-diverse waves). Cross-group shfl reduce
// (xor 16,32), then g==0 lanes do bias+ELU and write 32B each.
__global__ __launch_bounds__(256) void k_gat_agg8f(
    const unsigned char* __restrict__ Hf8, const int* __restrict__ rowptr,
    const int* __restrict__ col_s, const float* __restrict__ aS,
    const float* __restrict__ aD, const float* __restrict__ bias,
    __bf16* __restrict__ outh, int N) {
  int wid = (blockIdx.x * blockDim.x + threadIdx.x) >> 6;
  int lane = threadIdx.x & 63;
  if (wid >= N) return;
  int n = wid;
  int row0 = rowptr[n];
  int deg = rowptr[n + 1] - row0;
  int g = lane >> 4;   // edge group 0..3
  int c = lane & 15;   // channel block (16 fp8 = 16B)
  int head = c >> 1;
  float ad = aD[(size_t)n * 8 + head];
  f32x2 ap[8];
#pragma unroll
  for (int j = 0; j < 8; j++) ap[j] = (f32x2){0.f, 0.f};
  float den = 0.f;
  int dm1 = deg - 1;
  // prologue: full loads for iteration 0 (clamped -> always valid)
  int s0 = col_s[row0 + min(g, dm1)];
  int s1 = col_s[row0 + min(4 + g, dm1)];
  uint4 p0 = *(const uint4*)(Hf8 + (size_t)s0 * 256 + c * 16);
  uint4 p1 = *(const uint4*)(Hf8 + (size_t)s1 * 256 + c * 16);
  float a0 = aS[(size_t)s0 * 8 + head];
  float a1 = aS[(size_t)s1 * 8 + head];
  for (int i = 0; i < deg; i += 8) {
    // issue next iteration's loads (clamped, branch-free, always valid)
    int ns0 = col_s[row0 + min(i + 8 + g, dm1)];
    int ns1 = col_s[row0 + min(i + 12 + g, dm1)];
    uint4 np0 = *(const uint4*)(Hf8 + (size_t)ns0 * 256 + c * 16);
    uint4 np1 = *(const uint4*)(Hf8 + (size_t)ns1 * 256 + c * 16);
    float na0 = aS[(size_t)ns0 * 8 + head];
    float na1 = aS[(size_t)ns1 * 8 + head];
    // compute current iteration from data loaded last iteration
    float w0 = 0.f, w1 = 0.f;
    if (i + g < deg) {
      float x = a0 + ad;
      x = (x > 0.f) ? x : 0.2f * x;
      w0 = __expf(x);
    }
    if (i + 4 + g < deg) {
      float x = a1 + ad;
      x = (x > 0.f) ? x : 0.2f * x;
      w1 = __expf(x);
    }
    den += w0 + w1;
    f32x2 w02 = (f32x2){w0, w0};
    f32x2 w12 = (f32x2){w1, w1};
    __builtin_amdgcn_s_setprio(1);
    fma_fp8x4_pk(ap[0], ap[1], w02, p0.x);
    fma_fp8x4_pk(ap[2], ap[3], w02, p0.y);
    fma_fp8x4_pk(ap[4], ap[5], w02, p0.z);
    fma_fp8x4_pk(ap[6], ap[7], w02, p0.w);
    fma_fp8x4_pk(ap[0], ap[1], w12, p1.x);
    fma_fp8x4_pk(ap[2], ap[3], w12, p1.y);
    fma_fp8x4_pk(ap[4], ap[5], w12, p1.z);
    fma_fp8x4_pk(ap[6], ap[7], w12, p1.w);
    __builtin_amdgcn_s_setprio(0);
    p0 = np0;
    p1 = np1;
    a0 = na0;
    a1 = na1;
  }
  // reduce across the 4 edge-groups (lane bits 4,5)
#pragma unroll
  for (int off = 16; off < 64; off <<= 1) {
#pragma unroll
    for (int j = 0; j < 8; j++) {
      ap[j][0] += __shfl_xor(ap[j][0], off, 64);
      ap[j][1] += __shfl_xor(ap[j][1], off, 64);
    }
    den += __shfl_xor(den, off, 64);
  }
  if (g == 0) {
    float rsv = 1.f / den;  // deg >= 1 (self-loop), den > 0
    const float4* bp = (const float4*)(bias + c * 16);
    bf16x8 o0, o1;
#pragma unroll
    for (int wd = 0; wd < 4; wd++) {
      float4 bv = bp[wd];
      float v0 = ap[2 * wd][0] * rsv + bv.x;
      float v1 = ap[2 * wd][1] * rsv + bv.y;
      float v2 = ap[2 * wd + 1][0] * rsv + bv.z;
      float v3 = ap[2 * wd + 1][1] * rsv + bv.w;
      v0 = (v0 > 0.f) ? v0 : (__expf(v0) - 1.f);  // ELU
      v1 = (v1 > 0.f) ? v1 : (__expf(v1) - 1.f);
      v2 = (v2 > 0.f) ? v2 : (__expf(v2) - 1.f);
      v3 = (v3 > 0.f) ? v3 : (__expf(v3) - 1.f);
      if (wd < 2) {
        o0[wd * 4 + 0] = (__bf16)v0;
        o0[wd * 4 + 1] = (__bf16)v1;
        o0[wd * 4 + 2] = (__bf16)v2;
        o0[wd * 4 + 3] = (__bf16)v3;
      } else {
        o1[(wd - 2) * 4 + 0] = (__bf16)v0;
        o1[(wd - 2) * 4 + 1] = (__bf16)v1;
        o1[(wd - 2) * 4 + 2] = (__bf16)v2;
        o1[(wd - 2) * 4 + 3] = (__bf16)v3;
      }
    }
    *(bf16x8*)(outh + (size_t)n * 256 + c * 16) = o0;
    *(bf16x8*)(outh + (size_t)n * 256 + c * 16 + 8) = o1;
  }
}

// ---------------- GAT aggregation, H=1, fused alpha (layer 3) -----------
__global__ __launch_bounds__(256) void k_gat_agg1f(
    const __bf16* __restrict__ Hh, const int* __restrict__ rowptr,
    const int* __restrict__ col_s, const float* __restrict__ aS,
    const float* __restrict__ aD, const float* __restrict__ bias,
    float* __restrict__ out, int N) {
  int wid = (blockIdx.x * blockDim.x + threadIdx.x) >> 6;
  int lane = threadIdx.x & 63;
  if (wid >= N) return;
  int n = wid;
  int row0 = rowptr[n];
  int deg = rowptr[n + 1] - row0;
  int eo = lane >> 3;
  int cl = lane & 7;
  float ad = aD[n];
  f32x4 acc = (f32x4){0.f, 0.f, 0.f, 0.f};
  float den = 0.f;
  for (int i = eo; i < deg; i += 8) {
    int slot = row0 + i;
    int src = col_s[slot];
    float x = aS[src] + ad;
    x = (x > 0.f) ? x : 0.2f * x;
    float w = __expf(x);
    den += w;
    bf16x4 hv = *(const bf16x4*)(Hh + (size_t)src * 32 + cl * 4);
#pragma unroll
    for (int j = 0; j < 4; j++) acc[j] += w * (float)hv[j];
  }
#pragma unroll
  for (int off = 8; off < 64; off <<= 1) {
#pragma unroll
    for (int j = 0; j < 4; j++) acc[j] += __shfl_xor(acc[j], off, 64);
    den += __shfl_xor(den, off, 64);
  }
  if (eo == 0) {
    float rsv = 1.f / den;
#pragma unroll
    for (int j = 0; j < 4; j++)
      out[(size_t)n * 32 + cl * 4 + j] = acc[j] * rsv + bias[cl * 4 + j];
  }
}

// ---------------- fused mean-pool + linear ----------------
__global__ __launch_bounds__(256) void k_pool_final(
    const float* __restrict__ h, const int* __restrict__ batch,
    const float* __restrict__ linW, const float* __restrict__ linb,
    float* __restrict__ out, int N) {
  __shared__ float sh[256];
  int g = blockIdx.x;
  int tid = threadIdx.x;
  int grp = tid >> 5, c = tid & 31;
  int lo = 0, hi = N;
  while (lo < hi) { int mid = (lo + hi) >> 1; if (batch[mid] < g) lo = mid + 1; else hi = mid; }
  int start = lo;
  hi = N;
  while (lo < hi) { int mid = (lo + hi) >> 1; if (batch[mid] < g + 1) lo = mid + 1; else hi = mid; }
  int end = lo;
  float acc = 0.f;
  for (int n = start + grp; n < end; n += 8) acc += h[(size_t)n * 32 + c];
  sh[tid] = acc;
  __syncthreads();
  if (tid < 32) {
    float s = 0.f;
#pragma unroll
    for (int j = 0; j < 8; j++) s += sh[j * 32 + tid];
    float v = s * linW[tid];
#pragma unroll
    for (int off = 16; off > 0; off >>= 1) v += __shfl_xor(v, off, 64);
    if (tid == 0) {
      float cnt = (float)(end - start);
      out[g] = v / fmaxf(cnt, 1.f) + linb[0];
    }
  }
}

extern "C" void kernel_launch(void* const* d_in, const int* in_sizes, int n_in,
                              void* d_out, int out_size, void* d_ws, size_t ws_size,
                              hipStream_t stream) {
  const float* x = (const float*)d_in[0];
  const int* ei = (const int*)d_in[1];
  const int* batch = (const int*)d_in[2];
  const float* W1 = (const float*)d_in[3];
  const float* as1 = (const float*)d_in[4];
  const float* ad1 = (const float*)d_in[5];
  const float* b1 = (const float*)d_in[6];
  const float* W2 = (const float*)d_in[7];
  const float* as2 = (const float*)d_in[8];
  const float* ad2 = (const float*)d_in[9];
  const float* b2 = (const float*)d_in[10];
  const float* W3 = (const float*)d_in[11];
  const float* as3 = (const float*)d_in[12];
  const float* ad3 = (const float*)d_in[13];
  const float* b3 = (const float*)d_in[14];
  const float* linW = (const float*)d_in[15];
  const float* linb = (const float*)d_in[16];

  const int N = in_sizes[0] / 256;
  const int E = in_sizes[1] / 2;
  const int NUM_GRAPHS = 64;
  float* out = (float*)d_out;

  char* ws = (char*)d_ws;
  size_t off = 0;
  auto alloc = [&](size_t bytes) -> void* {
    void* p = ws + off;
    off += (bytes + 255) & ~(size_t)255;
    return p;
  };
  __bf16* Hh = (__bf16*)alloc((size_t)N * 256 * 2);  // layer-3 h (32 cols used)
  unsigned char* Hf8 = (unsigned char*)alloc((size_t)N * 256);  // fp8 copy
  __bf16* Ah = (__bf16*)alloc((size_t)N * 256 * 2);  // GEMM A in (bf16)
  float* aS = (float*)alloc((size_t)N * 8 * 4);
  float* aD = (float*)alloc((size_t)N * 8 * 4);
  int* deg = (int*)alloc((size_t)N * 4);
  int* rowptr = (int*)alloc((size_t)(N + 1) * 4);
  int* cursor = (int*)alloc((size_t)(N + 1) * 4);
  int* col_s = (int*)alloc((size_t)(E + N) * 4);  // src per CSR slot
  int* blockSums = (int*)alloc(256 * 4);
  int* blockOffs = (int*)alloc(256 * 4);
  __bf16* WT1h = (__bf16*)alloc(256 * 256 * 2);
  __bf16* WT2h = (__bf16*)alloc(256 * 256 * 2);
  __bf16* WT3h = (__bf16*)alloc(32 * 256 * 2);
  // h3agg reuses Ah (GEMM3 already consumed Ah when agg3 writes)
  float* h3agg = (float*)Ah;

  // --- merged prep (cast + 3 wpreps + init_deg) + CSR build ---
  {
    const int nCast = (N * 64 + 255) / 256;
    const int nPrep = nCast + 256 + 256 + 32 + (N + 255) / 256;
    k_prep<<<nPrep, 256, 0, stream>>>(x, Ah, W1, WT1h, W2, WT2h, W3, WT3h,
                                      deg, N);
  }
  {
    const int nch = 256;
    const int chunkSz = (E + nch - 1) / nch;
    k_count_deg_s<<<8 * nch, 256, 0, stream>>>(ei, E, N, deg, chunkSz);
  }
  const int nb = (N + 256 * SCAN_CH - 1) / (256 * SCAN_CH);  // 49 <= 256
  k_scan_partial<<<nb, 256, 0, stream>>>(deg, blockSums, N);
  k_scan_blocksums<<<1, 256, 0, stream>>>(blockSums, blockOffs, rowptr, nb, N);
  k_scan_final<<<nb, 256, 0, stream>>>(deg, blockOffs, rowptr, cursor, N);
  {
    const int totalItems = E + N;
    const int nch = 256;  // chunks per stripe; grid = 8*256 = 2048 blocks
    const int chunkSz = (totalItems + nch - 1) / nch;
    k_scatter2<<<8 * nch, 256, 0, stream>>>(ei, E, N, cursor, col_s, chunkSz);
  }

  const int aggBlocks = (N + 3) / 4;
  const int gemmBlocks = (N + 63) / 64;  // 64 rows/block, full 256-col width
  dim3 g3((N + 63) / 64);

  // --- layer 1 ---
  k_gemm_att<<<gemmBlocks, 256, 0, stream>>>(Ah, WT1h, as1, ad1, Hf8,
                                             aS, aD, N, 256);
  k_gat_agg8f<<<aggBlocks, 256, 0, stream>>>(Hf8, rowptr, col_s, aS, aD, b1,
                                             Ah, N);
  // --- layer 2 ---
  k_gemm_att<<<gemmBlocks, 256, 0, stream>>>(Ah, WT2h, as2, ad2, Hf8,
                                             aS, aD, N, 256);
  k_gat_agg8f<<<aggBlocks, 256, 0, stream>>>(Hf8, rowptr, col_s, aS, aD, b2,
                                             Ah, N);
  // --- layer 3 (H=1, bf16 gather, att fused into GEMM) ---
  k_gemm3_att<<<g3, 256, 0, stream>>>(Ah, WT3h, as3, ad3, Hh, aS, aD, N, 256);
  k_gat_agg1f<<<aggBlocks, 256, 0, stream>>>(Hh, rowptr, col_s, aS, aD, b3,
                                             h3agg, N);
  // --- pool + final ---
  k_pool_final<<<NUM_GRAPHS, 256, 0, stream>>>(h3agg, batch, linW, linb, out, N);
}

// Round 16
// 407.534 us; speedup vs baseline: 1.0321x; 1.0321x over previous
//
#include <hip/hip_runtime.h>
#include <hip/hip_fp8.h>
#include <math.h>

// ---------------------------------------------------------------------------
// GATClassifier on MI355X.
//   1. CSR build over dst: striped histogram -> 3-phase scan -> dst-striped
//      scatter (stripe = bid&7 pins each dst range's atomics+stores to one
//      XCD; heuristic only). col_s 4B only.
//   2. Per layer: MFMA GEMM h = bf16(A) @ bf16(B). R19 single-barrier
//      full-A-stage GEMM (64x256 A-strip in 32KB LDS, fragment-ordered,
//      barrier-free k-loop; R27 1-step B prefetch). R21 att dots fused into
//      epilogue. R25 dead Hh stores dropped. R26 Cf8 via LDS h-spill:
//      hw-packed (v_cvt_pk_fp8_f32) coalesced dwordx4 stores.
//      agg8f = R20 structure + R24 pk MAC + R27 index-prefetch pipeline.
//      R29: R28's 2-deep DATA pipeline REVERTED — +12 VGPR (28->40) dropped
//      occupancy 64->51%, agg8f 47.4->51.5us: for ~2-iter loops latency is
//      hidden by MORE WAVES, not deeper per-wave pipelines (same lesson as
//      R22). R27 index-only prefetch is the sweet spot.
//   3. Fused mean-pool + 32->1 linear (batch sorted -> binary search)
// History: R12 gemm 57x2. R14 drop Bl (512). R15 striped scatter (506).
// R18 drop lo-terms (488). R19 single-barrier GEMM (483). R20 agg8f fused
// alpha (463). R21 col_s + att-in-GEMM (448). R22 REGRESSED (455).
// R23 neutral (449). R24 pk_fma + layer3-att-fusion (442). R25 drop dead
// Hh stores + merged prep (428). R26 coalesced Cf8 epilogue (412).
// R27 index-prefetch pipelining (408). R28 2-deep pipe REGRESSED (421:
// VGPR/occupancy). R29 revert agg to R27.
// NOTE: edge_index / batch are int32.
// ---------------------------------------------------------------------------

typedef __attribute__((ext_vector_type(8))) __bf16 bf16x8;
typedef __attribute__((ext_vector_type(4))) __bf16 bf16x4;
typedef __attribute__((ext_vector_type(4))) float f32x4;
typedef __attribute__((ext_vector_type(2))) float f32x2;

#define SCAN_CH 4  // elements per thread in the device-wide scan

__device__ inline unsigned char f32_to_fp8(float f) {
  __hip_fp8_e4m3 v(f);
  return (unsigned char)v.__x;
}
__device__ inline float fp8_to_f32(unsigned char u) {
  __hip_fp8_e4m3 v;
  v.__x = (__hip_fp8_storage_t)u;
  return (float)v;
}

// Pack 4 f32 -> 4 fp8-e4m3 bytes in one dword (hw v_cvt_pk_fp8_f32 pair).
__device__ inline unsigned int pack4_fp8(float f0, float f1, float f2,
                                         float f3) {
#if defined(__has_builtin) && __has_builtin(__builtin_amdgcn_cvt_pk_fp8_f32)
  int w = 0;
  w = __builtin_amdgcn_cvt_pk_fp8_f32(f0, f1, w, false);  // bytes 0,1
  w = __builtin_amdgcn_cvt_pk_fp8_f32(f2, f3, w, true);   // bytes 2,3
  return (unsigned int)w;
#else
  return (unsigned int)f32_to_fp8(f0) | ((unsigned int)f32_to_fp8(f1) << 8) |
         ((unsigned int)f32_to_fp8(f2) << 16) |
         ((unsigned int)f32_to_fp8(f3) << 24);
#endif
}

// Decode 4 packed fp8 bytes -> 2 f32x2, packed-FMA into pair accumulators.
// f32x2 math maps to v_pk_fma_f32 (1 inst = 2 FMAs).
__device__ inline void fma_fp8x4_pk(f32x2& aLo, f32x2& aHi, f32x2 w2,
                                    unsigned int packed) {
#if defined(__has_builtin) && __has_builtin(__builtin_amdgcn_cvt_pk_f32_fp8)
  f32x2 lo = __builtin_amdgcn_cvt_pk_f32_fp8((int)packed, false);  // b0,b1
  f32x2 hi = __builtin_amdgcn_cvt_pk_f32_fp8((int)packed, true);   // b2,b3
  aLo = __builtin_elementwise_fma(lo, w2, aLo);
  aHi = __builtin_elementwise_fma(hi, w2, aHi);
#else
  aLo[0] += w2[0] * fp8_to_f32((unsigned char)(packed & 0xff));
  aLo[1] += w2[1] * fp8_to_f32((unsigned char)((packed >> 8) & 0xff));
  aHi[0] += w2[0] * fp8_to_f32((unsigned char)((packed >> 16) & 0xff));
  aHi[1] += w2[1] * fp8_to_f32((unsigned char)(packed >> 24));
#endif
}

// ---------------- merged prep: x cast + 3 W transposes + init_deg --------
__global__ __launch_bounds__(256) void k_prep(
    const float* __restrict__ x, __bf16* __restrict__ Ah,
    const float* __restrict__ W1, __bf16* __restrict__ WT1h,
    const float* __restrict__ W2, __bf16* __restrict__ WT2h,
    const float* __restrict__ W3, __bf16* __restrict__ WT3h,
    int* __restrict__ deg, int N) {
  int b = blockIdx.x;
  const int nCast = (N * 64 + 255) / 256;
  if (b < nCast) {  // cast x -> bf16 (float4 per thread)
    int i = b * 256 + threadIdx.x;
    if (i < N * 64) {
      float4 v = ((const float4*)x)[i];
      bf16x4 h;
      h[0] = (__bf16)v.x;
      h[1] = (__bf16)v.y;
      h[2] = (__bf16)v.z;
      h[3] = (__bf16)v.w;
      ((bf16x4*)Ah)[i] = h;
    }
    return;
  }
  b -= nCast;
  if (b < 256) {  // WT1: [256][256], i = n*256 + k
    int i = b * 256 + threadIdx.x;
    int n = i >> 8, k = i & 255;
    WT1h[i] = (__bf16)W1[k * 256 + n];
    return;
  }
  b -= 256;
  if (b < 256) {  // WT2
    int i = b * 256 + threadIdx.x;
    int n = i >> 8, k = i & 255;
    WT2h[i] = (__bf16)W2[k * 256 + n];
    return;
  }
  b -= 256;
  if (b < 32) {  // WT3: [32][256], Nc = 32
    int i = b * 256 + threadIdx.x;
    int n = i >> 8, k = i & 255;
    WT3h[i] = (__bf16)W3[k * 32 + n];
    return;
  }
  b -= 32;
  {  // init_deg
    int n = b * 256 + threadIdx.x;
    if (n < N) deg[n] = 1;  // self-loop
  }
}

// ---------------- CSR build ----------------
// dst-striped degree histogram (R23).
__global__ __launch_bounds__(256) void k_count_deg_s(const int* __restrict__ ei,
                                                     int E, int N, int* deg,
                                                     int chunkSz) {
  int stripe = blockIdx.x & 7;
  int chunk = blockIdx.x >> 3;
  int lo = (int)(((long long)N * stripe) >> 3);
  int hi = (int)(((long long)N * (stripe + 1)) >> 3);
  int base = chunk * chunkSz;
  int end = base + chunkSz;
  if (end > E) end = E;
  for (int i = base + threadIdx.x; i < end; i += 256) {
    int d = ei[E + i];
    if (d >= lo && d < hi) atomicAdd(&deg[d], 1);
  }
}

// --- 3-phase exclusive scan (R8: old single-block scan was 111us on 1 CU) ---
__global__ __launch_bounds__(256) void k_scan_partial(const int* __restrict__ deg,
                                                      int* __restrict__ blockSums,
                                                      int N) {
  __shared__ int sh[256];
  int t = threadIdx.x, b = blockIdx.x;
  int base = (b * 256 + t) * SCAN_CH;
  int s = 0;
#pragma unroll
  for (int j = 0; j < SCAN_CH; j++) {
    int idx = base + j;
    if (idx < N) s += deg[idx];
  }
  sh[t] = s;
  __syncthreads();
  for (int off = 128; off > 0; off >>= 1) {
    if (t < off) sh[t] += sh[t + off];
    __syncthreads();
  }
  if (t == 0) blockSums[b] = sh[0];
}

__global__ __launch_bounds__(256) void k_scan_blocksums(
    const int* __restrict__ blockSums, int* __restrict__ blockOffs,
    int* __restrict__ rowptr, int nb, int N) {
  __shared__ int sh[256];
  int t = threadIdx.x;
  int v = (t < nb) ? blockSums[t] : 0;
  sh[t] = v;
  __syncthreads();
  for (int off = 1; off < 256; off <<= 1) {
    int u = (t >= off) ? sh[t - off] : 0;
    __syncthreads();
    sh[t] += u;
    __syncthreads();
  }
  if (t < nb) blockOffs[t] = sh[t] - v;  // exclusive
  if (t == nb - 1) rowptr[N] = sh[t];    // total
}

__global__ __launch_bounds__(256) void k_scan_final(const int* __restrict__ deg,
                                                    const int* __restrict__ blockOffs,
                                                    int* __restrict__ rowptr,
                                                    int* __restrict__ cursor, int N) {
  __shared__ int sh[256];
  int t = threadIdx.x, b = blockIdx.x;
  int base = (b * 256 + t) * SCAN_CH;
  int vals[SCAN_CH];
  int s = 0;
#pragma unroll
  for (int j = 0; j < SCAN_CH; j++) {
    int idx = base + j;
    vals[j] = (idx < N) ? deg[idx] : 0;
    s += vals[j];
  }
  sh[t] = s;
  __syncthreads();
  for (int off = 1; off < 256; off <<= 1) {
    int u = (t >= off) ? sh[t - off] : 0;
    __syncthreads();
    sh[t] += u;
    __syncthreads();
  }
  int run = blockOffs[b] + sh[t] - s;  // exclusive prefix for this thread
#pragma unroll
  for (int j = 0; j < SCAN_CH; j++) {
    int idx = base + j;
    if (idx < N) {
      rowptr[idx] = run;
      cursor[idx] = run;
      run += vals[j];
    }
  }
}

// dst-striped scatter (R15/R21). Single 4B src store per edge.
__global__ __launch_bounds__(256) void k_scatter2(const int* __restrict__ ei,
                                                  int E, int N, int* cursor,
                                                  int* __restrict__ col_s,
                                                  int chunkSz) {
  int stripe = blockIdx.x & 7;
  int chunk = blockIdx.x >> 3;
  int lo = (int)(((long long)N * stripe) >> 3);
  int hi = (int)(((long long)N * (stripe + 1)) >> 3);
  int base = chunk * chunkSz;
  int end = base + chunkSz;
  int total = E + N;
  if (end > total) end = total;
  for (int i = base + threadIdx.x; i < end; i += 256) {
    int d = (i < E) ? ei[E + i] : (i - E);
    if (d < lo || d >= hi) continue;
    int s = (i < E) ? ei[i] : d;
    int pos = atomicAdd(&cursor[d], 1);
    col_s[pos] = s;
  }
}

// ------- LDS-shared MFMA GEMM + fused att dots (layers 1/2) --------------
// C = Ah @ Bh, plain bf16. Block = 64 rows x 256 cols (782 blocks, 4 waves).
// Stage the WHOLE 64x256 A-strip (32KB, fragment-ordered) up front, ONE
// barrier, barrier-free k-loop (R27: 1-step B prefetch; 4 B-loads + 4 LDS
// reads + 16 MFMAs/step). Epilogue (R26): barrier, spill h bf16 into sA,
// barrier, att dots + Cf8 hw-pack coalesced stores from the LDS copy.
// mfma_f32_16x16x32_bf16 (m89-verified): A: m=lane&15,k=quad*8+j;
// B: n=lane&15,k=quad*8+j (from WT); C/D: row=quad*4+reg, col=lane&15.
__global__ __launch_bounds__(256) void k_gemm_att(
    const __bf16* __restrict__ Ah, const __bf16* __restrict__ BTh,
    const float* __restrict__ attS, const float* __restrict__ attD,
    unsigned char* __restrict__ Cf8,
    float* __restrict__ aS, float* __restrict__ aD, int M, int K) {
  __shared__ __bf16 sA[64 * 256];  // 32 KB; reused for h spill after k-loop
  __shared__ float sAttS[256], sAttD[256];
  int tid = threadIdx.x;
  int lane = tid & 63, wave = tid >> 6;
  int quad = lane >> 4, l16 = lane & 15;
  int m0 = blockIdx.x * 64;
  int col0 = wave * 64;
  sAttS[tid] = attS[tid];  // 8 heads x 32 ch
  sAttD[tid] = attD[tid];
  // ---- stage all of A (8 rounds, coalesced, fragment-ordered) ----
  int srow = tid >> 2;                  // 0..63
  int mtw = srow >> 4, l16w = srow & 15;
  int arow = min(m0 + srow, M - 1);     // clamp: rows >= M never stored
  const __bf16* ag = Ah + (size_t)arow * K;
#pragma unroll
  for (int r = 0; r < 8; r++) {
    int c = (tid & 3) + r * 4;          // 8-elem chunk 0..31
    int s = c >> 2, q = c & 3;
    int slot = (((s * 4 + mtw) * 4 + q) * 16 + l16w) * 8;
    *(bf16x8*)(sA + slot) = *(const bf16x8*)(ag + c * 8);
  }
  __syncthreads();
  const __bf16* brh = BTh + (size_t)(col0 + l16) * K + quad * 8;
  f32x4 acc[4][4];  // [mt][nt]
#pragma unroll
  for (int mt = 0; mt < 4; mt++)
#pragma unroll
    for (int t = 0; t < 4; t++) acc[mt][t] = (f32x4){0.f, 0.f, 0.f, 0.f};
  bf16x8 b_h[4], b_n[4];
#pragma unroll
  for (int t = 0; t < 4; t++)
    b_h[t] = *(const bf16x8*)(brh + (size_t)t * 16 * K);
  for (int s = 0; s < 8; s++) {  // k0 = s*32; no barriers inside
    if (s < 7) {  // prefetch B(s+1); lands under this step's MFMAs
#pragma unroll
      for (int t = 0; t < 4; t++)
        b_n[t] = *(const bf16x8*)(brh + (size_t)t * 16 * K + (s + 1) * 32);
    }
    bf16x8 a_h[4];
#pragma unroll
    for (int mt = 0; mt < 4; mt++)
      a_h[mt] = *(const bf16x8*)(sA + (((s * 4 + mt) * 4 + quad) * 16 + l16) * 8);
#pragma unroll
    for (int t = 0; t < 4; t++) {
#pragma unroll
      for (int mt = 0; mt < 4; mt++) {
        acc[mt][t] = __builtin_amdgcn_mfma_f32_16x16x32_bf16(a_h[mt], b_h[t], acc[mt][t], 0, 0, 0);
      }
    }
#pragma unroll
    for (int t = 0; t < 4; t++) b_h[t] = b_n[t];
  }
  __syncthreads();  // all sA (A-tile) reads done; safe to overwrite with h
#pragma unroll
  for (int mt = 0; mt < 4; mt++) {
#pragma unroll
    for (int t = 0; t < 4; t++) {
#pragma unroll
      for (int r = 0; r < 4; r++) {
        int row = mt * 16 + quad * 4 + r;
        sA[row * 256 + col0 + t * 16 + l16] = (__bf16)acc[mt][t][r];
      }
    }
  }
  __syncthreads();
  // ---- att dots: 512 tasks = (row 0..63, head 0..7), 2 per thread ----
#pragma unroll
  for (int u = 0; u < 2; u++) {
    int task = tid + u * 256;
    int row = task >> 3, h = task & 7;
    const __bf16* hr = sA + row * 256 + h * 32;
    float ss = 0.f, dd = 0.f;
#pragma unroll
    for (int k = 0; k < 4; k++) {
      bf16x8 a = *(const bf16x8*)(hr + k * 8);
#pragma unroll
      for (int j = 0; j < 8; j++) {
        float v = (float)a[j];
        ss += v * sAttS[h * 32 + k * 8 + j];
        dd += v * sAttD[h * 32 + k * 8 + j];
      }
    }
    int m = m0 + row;
    if (m < M) {
      aS[(size_t)m * 8 + h] = ss;
      aD[(size_t)m * 8 + h] = dd;
    }
  }
  // ---- Cf8 from LDS: 1024 16B segments, 4 per thread, coalesced ----
#pragma unroll
  for (int u = 0; u < 4; u++) {
    int seg = tid + u * 256;       // 0..1023
    int row = seg >> 4;            // 0..63
    int sc = (seg & 15) * 16;      // col start (16 fp8 = 16B)
    int m = m0 + row;
    if (m < M) {
      const __bf16* hp = sA + row * 256 + sc;
      bf16x8 h0 = *(const bf16x8*)hp;
      bf16x8 h1 = *(const bf16x8*)(hp + 8);
      uint4 w;
      w.x = pack4_fp8((float)h0[0], (float)h0[1], (float)h0[2], (float)h0[3]);
      w.y = pack4_fp8((float)h0[4], (float)h0[5], (float)h0[6], (float)h0[7]);
      w.z = pack4_fp8((float)h1[0], (float)h1[1], (float)h1[2], (float)h1[3]);
      w.w = pack4_fp8((float)h1[4], (float)h1[5], (float)h1[6], (float)h1[7]);
      *(uint4*)(Cf8 + (size_t)m * 256 + sc) = w;
    }
  }
}

// ------- MFMA GEMM + fused att (layer 3, H=1, R24) -----------------------
// 64 rows/block (4 waves x 16 rows), all 32 cols in-register (NT=2).
// After C store: aS/aD dots = 2 fma + 16-lane shfl reduce per row.
__global__ __launch_bounds__(256) void k_gemm3_att(
    const __bf16* __restrict__ Ah, const __bf16* __restrict__ BTh,
    const float* __restrict__ attS, const float* __restrict__ attD,
    __bf16* __restrict__ Ch, float* __restrict__ aS, float* __restrict__ aD,
    int M, int K) {
  int lane = threadIdx.x & 63;
  int wave = threadIdx.x >> 6;
  int quad = lane >> 4;
  int l16 = lane & 15;
  int m0 = blockIdx.x * 64 + wave * 16;
  int am = min(m0 + l16, M - 1);
  const __bf16* arh = Ah + (size_t)am * K + quad * 8;
  const __bf16* brh = BTh + (size_t)l16 * K + quad * 8;
  f32x4 acc0 = (f32x4){0.f, 0.f, 0.f, 0.f};
  f32x4 acc1 = (f32x4){0.f, 0.f, 0.f, 0.f};
  for (int k0 = 0; k0 < K; k0 += 32) {
    bf16x8 a = *(const bf16x8*)(arh + k0);
    bf16x8 b0 = *(const bf16x8*)(brh + k0);
    bf16x8 b1 = *(const bf16x8*)(brh + (size_t)16 * K + k0);
    acc0 = __builtin_amdgcn_mfma_f32_16x16x32_bf16(a, b0, acc0, 0, 0, 0);
    acc1 = __builtin_amdgcn_mfma_f32_16x16x32_bf16(a, b1, acc1, 0, 0, 0);
  }
#pragma unroll
  for (int r = 0; r < 4; r++) {
    int m = m0 + quad * 4 + r;
    if (m < M) {
      Ch[(size_t)m * 32 + l16] = (__bf16)acc0[r];
      Ch[(size_t)m * 32 + 16 + l16] = (__bf16)acc1[r];
    }
  }
  float s0 = attS[l16], s1 = attS[16 + l16];
  float d0 = attD[l16], d1 = attD[16 + l16];
#pragma unroll
  for (int r = 0; r < 4; r++) {
    float ss = acc0[r] * s0 + acc1[r] * s1;
    float dd = acc0[r] * d0 + acc1[r] * d1;
#pragma unroll
    for (int off = 1; off < 16; off <<= 1) {
      ss += __shfl_xor(ss, off, 64);
      dd += __shfl_xor(dd, off, 64);
    }
    int m = m0 + quad * 4 + r;
    if (l16 == 0 && m < M) {
      aS[m] = ss;
      aD[m] = dd;
    }
  }
}

// ------- GAT aggregation, H=8 (R20 + R24 pk MAC + R27 pipe) --------------
// wave per node. lane = (edge-group g = lane>>4, channel-block c = lane&15:
// 16 fp8 channels = one dwordx4). One gather instruction serves 4 edges.
// w = exp(leaky(aS[s*8+head] + aD[n*8+head])) inline (head = c>>1; aS
// 1.6MB L2-resident). MAC via f32x2 packed FMA. R27: next iteration's
// col_s pair prefetched (clamped, branch-free) so gathers issue at loop
// top without waiting on the index load. (R28's 2-deep DATA pipeline
// regressed: +12 VGPR -> occupancy 64->51%.) Cross-group shfl reduce
// (xor 16,32), then g==0 lanes do bias+ELU and write 32B each.
__global__ __launch_bounds__(256) void k_gat_agg8f(
    const unsigned char* __restrict__ Hf8, const int* __restrict__ rowptr,
    const int* __restrict__ col_s, const float* __restrict__ aS,
    const float* __restrict__ aD, const float* __restrict__ bias,
    __bf16* __restrict__ outh, int N) {
  int wid = (blockIdx.x * blockDim.x + threadIdx.x) >> 6;
  int lane = threadIdx.x & 63;
  if (wid >= N) return;
  int n = wid;
  int row0 = rowptr[n];
  int deg = rowptr[n + 1] - row0;
  int g = lane >> 4;   // edge group 0..3
  int c = lane & 15;   // channel block (16 fp8 = 16B)
  int head = c >> 1;
  float ad = aD[(size_t)n * 8 + head];
  f32x2 ap[8];
#pragma unroll
  for (int j = 0; j < 8; j++) ap[j] = (f32x2){0.f, 0.f};
  float den = 0.f;
  int dm1 = deg - 1;
  // prologue: indices for iteration 0 (clamped -> always valid)
  int s0 = col_s[row0 + min(g, dm1)];
  int s1 = col_s[row0 + min(4 + g, dm1)];
  for (int i = 0; i < deg; i += 8) {
    // prefetch next iteration's indices (clamped, branch-free)
    int ns0 = col_s[row0 + min(i + 8 + g, dm1)];
    int ns1 = col_s[row0 + min(i + 12 + g, dm1)];
    int e0 = i + g, e1 = i + 4 + g;
    uint4 p0 = *(const uint4*)(Hf8 + (size_t)s0 * 256 + c * 16);
    uint4 p1 = *(const uint4*)(Hf8 + (size_t)s1 * 256 + c * 16);
    float w0 = 0.f, w1 = 0.f;
    if (e0 < deg) {
      float x = aS[(size_t)s0 * 8 + head] + ad;
      x = (x > 0.f) ? x : 0.2f * x;
      w0 = __expf(x);
    }
    if (e1 < deg) {
      float x = aS[(size_t)s1 * 8 + head] + ad;
      x = (x > 0.f) ? x : 0.2f * x;
      w1 = __expf(x);
    }
    den += w0 + w1;
    f32x2 w02 = (f32x2){w0, w0};
    f32x2 w12 = (f32x2){w1, w1};
    fma_fp8x4_pk(ap[0], ap[1], w02, p0.x);
    fma_fp8x4_pk(ap[2], ap[3], w02, p0.y);
    fma_fp8x4_pk(ap[4], ap[5], w02, p0.z);
    fma_fp8x4_pk(ap[6], ap[7], w02, p0.w);
    fma_fp8x4_pk(ap[0], ap[1], w12, p1.x);
    fma_fp8x4_pk(ap[2], ap[3], w12, p1.y);
    fma_fp8x4_pk(ap[4], ap[5], w12, p1.z);
    fma_fp8x4_pk(ap[6], ap[7], w12, p1.w);
    s0 = ns0;
    s1 = ns1;
  }
  // reduce across the 4 edge-groups (lane bits 4,5)
#pragma unroll
  for (int off = 16; off < 64; off <<= 1) {
#pragma unroll
    for (int j = 0; j < 8; j++) {
      ap[j][0] += __shfl_xor(ap[j][0], off, 64);
      ap[j][1] += __shfl_xor(ap[j][1], off, 64);
    }
    den += __shfl_xor(den, off, 64);
  }
  if (g == 0) {
    float rsv = 1.f / den;  // deg >= 1 (self-loop), den > 0
    const float4* bp = (const float4*)(bias + c * 16);
    bf16x8 o0, o1;
#pragma unroll
    for (int wd = 0; wd < 4; wd++) {
      float4 bv = bp[wd];
      float v0 = ap[2 * wd][0] * rsv + bv.x;
      float v1 = ap[2 * wd][1] * rsv + bv.y;
      float v2 = ap[2 * wd + 1][0] * rsv + bv.z;
      float v3 = ap[2 * wd + 1][1] * rsv + bv.w;
      v0 = (v0 > 0.f) ? v0 : (__expf(v0) - 1.f);  // ELU
      v1 = (v1 > 0.f) ? v1 : (__expf(v1) - 1.f);
      v2 = (v2 > 0.f) ? v2 : (__expf(v2) - 1.f);
      v3 = (v3 > 0.f) ? v3 : (__expf(v3) - 1.f);
      if (wd < 2) {
        o0[wd * 4 + 0] = (__bf16)v0;
        o0[wd * 4 + 1] = (__bf16)v1;
        o0[wd * 4 + 2] = (__bf16)v2;
        o0[wd * 4 + 3] = (__bf16)v3;
      } else {
        o1[(wd - 2) * 4 + 0] = (__bf16)v0;
        o1[(wd - 2) * 4 + 1] = (__bf16)v1;
        o1[(wd - 2) * 4 + 2] = (__bf16)v2;
        o1[(wd - 2) * 4 + 3] = (__bf16)v3;
      }
    }
    *(bf16x8*)(outh + (size_t)n * 256 + c * 16) = o0;
    *(bf16x8*)(outh + (size_t)n * 256 + c * 16 + 8) = o1;
  }
}

// ---------------- GAT aggregation, H=1, fused alpha (layer 3) -----------
__global__ __launch_bounds__(256) void k_gat_agg1f(
    const __bf16* __restrict__ Hh, const int* __restrict__ rowptr,
    const int* __restrict__ col_s, const float* __restrict__ aS,
    const float* __restrict__ aD, const float* __restrict__ bias,
    float* __restrict__ out, int N) {
  int wid = (blockIdx.x * blockDim.x + threadIdx.x) >> 6;
  int lane = threadIdx.x & 63;
  if (wid >= N) return;
  int n = wid;
  int row0 = rowptr[n];
  int deg = rowptr[n + 1] - row0;
  int eo = lane >> 3;
  int cl = lane & 7;
  float ad = aD[n];
  f32x4 acc = (f32x4){0.f, 0.f, 0.f, 0.f};
  float den = 0.f;
  for (int i = eo; i < deg; i += 8) {
    int slot = row0 + i;
    int src = col_s[slot];
    float x = aS[src] + ad;
    x = (x > 0.f) ? x : 0.2f * x;
    float w = __expf(x);
    den += w;
    bf16x4 hv = *(const bf16x4*)(Hh + (size_t)src * 32 + cl * 4);
#pragma unroll
    for (int j = 0; j < 4; j++) acc[j] += w * (float)hv[j];
  }
#pragma unroll
  for (int off = 8; off < 64; off <<= 1) {
#pragma unroll
    for (int j = 0; j < 4; j++) acc[j] += __shfl_xor(acc[j], off, 64);
    den += __shfl_xor(den, off, 64);
  }
  if (eo == 0) {
    float rsv = 1.f / den;
#pragma unroll
    for (int j = 0; j < 4; j++)
      out[(size_t)n * 32 + cl * 4 + j] = acc[j] * rsv + bias[cl * 4 + j];
  }
}

// ---------------- fused mean-pool + linear ----------------
__global__ __launch_bounds__(256) void k_pool_final(
    const float* __restrict__ h, const int* __restrict__ batch,
    const float* __restrict__ linW, const float* __restrict__ linb,
    float* __restrict__ out, int N) {
  __shared__ float sh[256];
  int g = blockIdx.x;
  int tid = threadIdx.x;
  int grp = tid >> 5, c = tid & 31;
  int lo = 0, hi = N;
  while (lo < hi) { int mid = (lo + hi) >> 1; if (batch[mid] < g) lo = mid + 1; else hi = mid; }
  int start = lo;
  hi = N;
  while (lo < hi) { int mid = (lo + hi) >> 1; if (batch[mid] < g + 1) lo = mid + 1; else hi = mid; }
  int end = lo;
  float acc = 0.f;
  for (int n = start + grp; n < end; n += 8) acc += h[(size_t)n * 32 + c];
  sh[tid] = acc;
  __syncthreads();
  if (tid < 32) {
    float s = 0.f;
#pragma unroll
    for (int j = 0; j < 8; j++) s += sh[j * 32 + tid];
    float v = s * linW[tid];
#pragma unroll
    for (int off = 16; off > 0; off >>= 1) v += __shfl_xor(v, off, 64);
    if (tid == 0) {
      float cnt = (float)(end - start);
      out[g] = v / fmaxf(cnt, 1.f) + linb[0];
    }
  }
}

extern "C" void kernel_launch(void* const* d_in, const int* in_sizes, int n_in,
                              void* d_out, int out_size, void* d_ws, size_t ws_size,
                              hipStream_t stream) {
  const float* x = (const float*)d_in[0];
  const int* ei = (const int*)d_in[1];
  const int* batch = (const int*)d_in[2];
  const float* W1 = (const float*)d_in[3];
  const float* as1 = (const float*)d_in[4];
  const float* ad1 = (const float*)d_in[5];
  const float* b1 = (const float*)d_in[6];
  const float* W2 = (const float*)d_in[7];
  const float* as2 = (const float*)d_in[8];
  const float* ad2 = (const float*)d_in[9];
  const float* b2 = (const float*)d_in[10];
  const float* W3 = (const float*)d_in[11];
  const float* as3 = (const float*)d_in[12];
  const float* ad3 = (const float*)d_in[13];
  const float* b3 = (const float*)d_in[14];
  const float* linW = (const float*)d_in[15];
  const float* linb = (const float*)d_in[16];

  const int N = in_sizes[0] / 256;
  const int E = in_sizes[1] / 2;
  const int NUM_GRAPHS = 64;
  float* out = (float*)d_out;

  char* ws = (char*)d_ws;
  size_t off = 0;
  auto alloc = [&](size_t bytes) -> void* {
    void* p = ws + off;
    off += (bytes + 255) & ~(size_t)255;
    return p;
  };
  __bf16* Hh = (__bf16*)alloc((size_t)N * 256 * 2);  // layer-3 h (32 cols used)
  unsigned char* Hf8 = (unsigned char*)alloc((size_t)N * 256);  // fp8 copy
  __bf16* Ah = (__bf16*)alloc((size_t)N * 256 * 2);  // GEMM A in (bf16)
  float* aS = (float*)alloc((size_t)N * 8 * 4);
  float* aD = (float*)alloc((size_t)N * 8 * 4);
  int* deg = (int*)alloc((size_t)N * 4);
  int* rowptr = (int*)alloc((size_t)(N + 1) * 4);
  int* cursor = (int*)alloc((size_t)(N + 1) * 4);
  int* col_s = (int*)alloc((size_t)(E + N) * 4);  // src per CSR slot
  int* blockSums = (int*)alloc(256 * 4);
  int* blockOffs = (int*)alloc(256 * 4);
  __bf16* WT1h = (__bf16*)alloc(256 * 256 * 2);
  __bf16* WT2h = (__bf16*)alloc(256 * 256 * 2);
  __bf16* WT3h = (__bf16*)alloc(32 * 256 * 2);
  // h3agg reuses Ah (GEMM3 already consumed Ah when agg3 writes)
  float* h3agg = (float*)Ah;

  // --- merged prep (cast + 3 wpreps + init_deg) + CSR build ---
  {
    const int nCast = (N * 64 + 255) / 256;
    const int nPrep = nCast + 256 + 256 + 32 + (N + 255) / 256;
    k_prep<<<nPrep, 256, 0, stream>>>(x, Ah, W1, WT1h, W2, WT2h, W3, WT3h,
                                      deg, N);
  }
  {
    const int nch = 256;
    const int chunkSz = (E + nch - 1) / nch;
    k_count_deg_s<<<8 * nch, 256, 0, stream>>>(ei, E, N, deg, chunkSz);
  }
  const int nb = (N + 256 * SCAN_CH - 1) / (256 * SCAN_CH);  // 49 <= 256
  k_scan_partial<<<nb, 256, 0, stream>>>(deg, blockSums, N);
  k_scan_blocksums<<<1, 256, 0, stream>>>(blockSums, blockOffs, rowptr, nb, N);
  k_scan_final<<<nb, 256, 0, stream>>>(deg, blockOffs, rowptr, cursor, N);
  {
    const int totalItems = E + N;
    const int nch = 256;  // chunks per stripe; grid = 8*256 = 2048 blocks
    const int chunkSz = (totalItems + nch - 1) / nch;
    k_scatter2<<<8 * nch, 256, 0, stream>>>(ei, E, N, cursor, col_s, chunkSz);
  }

  const int aggBlocks = (N + 3) / 4;
  const int gemmBlocks = (N + 63) / 64;  // 64 rows/block, full 256-col width
  dim3 g3((N + 63) / 64);

  // --- layer 1 ---
  k_gemm_att<<<gemmBlocks, 256, 0, stream>>>(Ah, WT1h, as1, ad1, Hf8,
                                             aS, aD, N, 256);
  k_gat_agg8f<<<aggBlocks, 256, 0, stream>>>(Hf8, rowptr, col_s, aS, aD, b1,
                                             Ah, N);
  // --- layer 2 ---
  k_gemm_att<<<gemmBlocks, 256, 0, stream>>>(Ah, WT2h, as2, ad2, Hf8,
                                             aS, aD, N, 256);
  k_gat_agg8f<<<aggBlocks, 256, 0, stream>>>(Hf8, rowptr, col_s, aS, aD, b2,
                                             Ah, N);
  // --- layer 3 (H=1, bf16 gather, att fused into GEMM) ---
  k_gemm3_att<<<g3, 256, 0, stream>>>(Ah, WT3h, as3, ad3, Hh, aS, aD, N, 256);
  k_gat_agg1f<<<aggBlocks, 256, 0, stream>>>(Hh, rowptr, col_s, aS, aD, b3,
                                             h3agg, N);
  // --- pool + final ---
  k_pool_final<<<NUM_GRAPHS, 256, 0, stream>>>(h3agg, batch, linW, linb, out, N);
}